// Round 3
// baseline (251.160 us; speedup 1.0000x reference)
//
#include <hip/hip_runtime.h>

#define EPS 1e-5f
#define WAVES 4

typedef __attribute__((ext_vector_type(8)))  short short8;
typedef __attribute__((ext_vector_type(4)))  short short4_t;
typedef __attribute__((ext_vector_type(16))) float f32x16;
typedef __attribute__((ext_vector_type(4)))  float f32x4;

__device__ inline unsigned f2bf(float f) {
    unsigned u = __builtin_bit_cast(unsigned, f);
    return (u + 0x7fffu + ((u >> 16) & 1u)) >> 16;   // RNE f32->bf16
}

// Repack w2 [k][n] f32 row-major -> bf16, MFMA-fragment order:
// w2f[((nf*16+ks)*64 + lane)*8 + e] = bf16(w2[ks*16+(lane>>5)*8+e][nf*32+(lane&31)])
__global__ void prep_w2(const float* __restrict__ w2, unsigned short* __restrict__ w2f) {
    int idx  = blockIdx.x * 256 + threadIdx.x;          // 65536 elements
    int e    = idx & 7;
    int lane = (idx >> 3) & 63;
    int ks   = (idx >> 9) & 15;
    int nf   = idx >> 13;
    int k    = ks * 16 + (lane >> 5) * 8 + e;
    int n    = nf * 32 + (lane & 31);
    w2f[idx] = (unsigned short)f2bf(w2[k * 256 + n]);
}

__global__ __launch_bounds__(256, 2) void fused_kernel(
    const int* __restrict__ z, const float* __restrict__ x,
    const float* __restrict__ emb, const float* __restrict__ w1,
    const float* __restrict__ b1, const unsigned short* __restrict__ w2f,
    const float* __restrict__ b2, const float* __restrict__ gamma,
    const float* __restrict__ beta, float* __restrict__ out, int N)
{
    // All LDS is PER-WAVE: no __syncthreads anywhere (within-wave producer/consumer,
    // DS pipe is in-order per wave; compiler inserts lgkmcnt waits).
    __shared__ char  p_lds[WAVES * 16384];   // per-wave: 32x256 bf16 A-tile, then 16x256 f32 store-stage
    __shared__ float x_lds[WAVES][32][4];
    __shared__ int   z_lds[WAVES][32];

    const int tid  = threadIdx.x;
    const int wave = tid >> 6;
    const int lane = tid & 63;
    const int l31  = lane & 31;
    const int h    = lane >> 5;
    char* pbuf = p_lds + wave * 16384;

    const int tiles = N >> 5;
    const int t = blockIdx.x * WAVES + wave;
    if (t >= tiles) return;                  // per-wave exit legal: no barriers
    const int R = t << 5;

    // stage x rows + z for this wave's 32-row tile
    if (lane < 32) {
        int r = R + lane;
        x_lds[wave][lane][0] = x[r * 3 + 0];
        x_lds[wave][lane][1] = x[r * 3 + 1];
        x_lds[wave][lane][2] = x[r * 3 + 2];
        z_lds[wave][lane]    = z[r];
    }

    // ---- init accumulator with the embedding gather (C/D layout): the 128
    // coalesced L2-hit loads fly while the silu chain below executes.
    f32x16 acc[8];
#pragma unroll
    for (int j = 0; j < 16; ++j) {
        const int rl = (j & 3) + ((j >> 2) << 3) + (h << 2);
        const float* er = emb + (size_t)z_lds[wave][rl] * 256 + l31;
#pragma unroll
        for (int nf = 0; nf < 8; ++nf)
            acc[nf][j] = er[nf * 32];
    }

    // hoisted per-lane weights: this lane computes p columns [lane*4, lane*4+3]
    const int  c0  = lane * 4;
    const f32x4 w1a = *(const f32x4*)(w1 + c0);
    const f32x4 w1b = *(const f32x4*)(w1 + 256 + c0);
    const f32x4 w1c = *(const f32x4*)(w1 + 512 + c0);
    const f32x4 b1v = *(const f32x4*)(b1 + c0);
    float b2v[8], gv[8], bv[8];
#pragma unroll
    for (int nf = 0; nf < 8; ++nf) {
        int c = nf * 32 + l31;
        b2v[nf] = b2[c]; gv[nf] = gamma[c]; bv[nf] = beta[c];
    }

    // p = silu(x @ w1 + b1) -> bf16 LDS tile, XOR-swizzled rows
#pragma unroll
    for (int r = 0; r < 32; ++r) {
        float x0 = x_lds[wave][r][0];
        float x1 = x_lds[wave][r][1];
        float x2 = x_lds[wave][r][2];
        short4_t pv;
#pragma unroll
        for (int j = 0; j < 4; ++j) {
            float tv = x0 * w1a[j] + x1 * w1b[j] + x2 * w1c[j] + b1v[j];
            float s  = tv * __builtin_amdgcn_rcpf(1.f + __expf(-tv));
            pv[j] = (short)f2bf(s);
        }
        int off = (r * 512 + lane * 8) ^ ((r & 7) << 4);
        *(short4_t*)(pbuf + off) = pv;
    }

    // GEMM: [32,256] @ [256,256] via mfma_f32_32x32x16_bf16 (acc pre-loaded with emb)
#pragma unroll
    for (int ks = 0; ks < 16; ++ks) {
        int aoff = (l31 * 512 + ks * 32 + h * 16) ^ ((l31 & 7) << 4);
        short8 a = *(const short8*)(pbuf + aoff);
        const unsigned short* bp = w2f + ks * 512 + lane * 8;
#pragma unroll
        for (int nf = 0; nf < 8; ++nf) {
            short8 b = *(const short8*)(bp + nf * 8192);
            acc[nf] = __builtin_amdgcn_mfma_f32_32x32x16_bf16(a, b, acc[nf], 0, 0, 0);
        }
    }

    // ---- epilogue: h = acc + b2 ; LayerNorm ; transpose-stage through LDS so
    // every global store is one FULL 1KB row (64 lanes x 16B) -> no write-RFO.
    float* pf = (float*)pbuf;     // A-tile is dead after the MFMA loop; reuse as [16][256] f32
#pragma unroll
    for (int half = 0; half < 2; ++half) {
#pragma unroll
        for (int jj = 0; jj < 8; ++jj) {
            const int j  = half * 8 + jj;
            const int rl = (j & 3) + ((j >> 2) << 3) + (h << 2);   // row within 32
            float hv[8];
            float hsum = 0.f, hsq = 0.f;
#pragma unroll
            for (int nf = 0; nf < 8; ++nf) {
                float v = acc[nf][j] + b2v[nf];
                hv[nf] = v; hsum += v; hsq += v * v;
            }
#pragma unroll
            for (int d = 1; d < 32; d <<= 1) {    // row lives in one lane-half
                hsum += __shfl_xor(hsum, d, 64);
                hsq  += __shfl_xor(hsq,  d, 64);
            }
            float mu  = hsum * (1.f / 256.f);
            float var = hsq * (1.f / 256.f) - mu * mu;
            float rs  = rsqrtf(var + EPS);
            float* prow = pf + (rl & 15) * 256 + l31;   // banks = l31: conflict-free
#pragma unroll
            for (int nf = 0; nf < 8; ++nf)
                prow[nf * 32] = (hv[nf] - mu) * rs * gv[nf] + bv[nf];
        }
        // flush 16 rows: one full 1KB row per store instruction (fully coalesced)
#pragma unroll
        for (int rr = 0; rr < 16; ++rr) {
            f32x4 v = *(const f32x4*)(pf + rr * 256 + lane * 4);
            *(f32x4*)(out + (size_t)(R + half * 16 + rr) * 256 + lane * 4) = v;
        }
    }
}

extern "C" void kernel_launch(void* const* d_in, const int* in_sizes, int n_in,
                              void* d_out, int out_size, void* d_ws, size_t ws_size,
                              hipStream_t stream) {
    const int*   z     = (const int*)d_in[0];
    const float* x     = (const float*)d_in[1];
    const float* emb   = (const float*)d_in[2];
    const float* w1    = (const float*)d_in[3];
    const float* b1    = (const float*)d_in[4];
    const float* w2    = (const float*)d_in[5];
    const float* b2    = (const float*)d_in[6];
    const float* gamma = (const float*)d_in[7];
    const float* beta  = (const float*)d_in[8];
    float* out = (float*)d_out;
    const int N = in_sizes[0];

    unsigned short* w2f = (unsigned short*)d_ws;   // 128 KB fragment-ordered bf16 w2

    prep_w2<<<256, 256, 0, stream>>>(w2, w2f);

    int tiles  = N >> 5;
    int blocks = (tiles + WAVES - 1) / WAVES;      // one tile-group per block
    fused_kernel<<<blocks, 256, 0, stream>>>(z, x, emb, w1, b1, w2f, b2, gamma, beta, out, N);
}

// Round 4
// 189.801 us; speedup vs baseline: 1.3233x; 1.3233x over previous
//
#include <hip/hip_runtime.h>

#define EPS 1e-5f
#define WAVES 4

typedef __attribute__((ext_vector_type(8)))  short short8;
typedef __attribute__((ext_vector_type(4)))  short short4_t;
typedef __attribute__((ext_vector_type(16))) float f32x16;
typedef __attribute__((ext_vector_type(4)))  float f32x4;

__device__ inline unsigned f2bf(float f) {
    unsigned u = __builtin_bit_cast(unsigned, f);
    return (u + 0x7fffu + ((u >> 16) & 1u)) >> 16;   // RNE f32->bf16
}

// Repack w2 [k][n] f32 row-major -> bf16, MFMA-fragment order:
// w2f[((nf*16+ks)*64 + lane)*8 + e] = bf16(w2[ks*16+(lane>>5)*8+e][nf*32+(lane&31)])
__global__ void prep_w2(const float* __restrict__ w2, unsigned short* __restrict__ w2f) {
    int idx  = blockIdx.x * 256 + threadIdx.x;          // 65536 elements
    int e    = idx & 7;
    int lane = (idx >> 3) & 63;
    int ks   = (idx >> 9) & 15;
    int nf   = idx >> 13;
    int k    = ks * 16 + (lane >> 5) * 8 + e;
    int n    = nf * 32 + (lane & 31);
    w2f[idx] = (unsigned short)f2bf(w2[k * 256 + n]);
}

__global__ __launch_bounds__(256, 2) void fused_kernel(
    const int* __restrict__ z, const float* __restrict__ x,
    const float* __restrict__ emb, const float* __restrict__ w1,
    const float* __restrict__ b1, const unsigned short* __restrict__ w2f,
    const float* __restrict__ b2, const float* __restrict__ gamma,
    const float* __restrict__ beta, float* __restrict__ out, int N)
{
    // All LDS is PER-WAVE: no __syncthreads anywhere (within-wave producer/consumer,
    // DS pipe is in-order per wave; compiler inserts lgkmcnt waits).
    __shared__ char  p_lds[WAVES * 16384];   // per-wave 32x256 bf16 A-tile (swizzled)
    __shared__ float x_lds[WAVES][32][4];
    __shared__ int   z_lds[WAVES][32];

    const int tid  = threadIdx.x;
    const int wave = tid >> 6;
    const int lane = tid & 63;
    const int l31  = lane & 31;
    const int h    = lane >> 5;
    char* pbuf = p_lds + wave * 16384;

    const int tiles = N >> 5;
    const int t = blockIdx.x * WAVES + wave;
    if (t >= tiles) return;                  // per-wave exit legal: no barriers
    const int R = t << 5;

    // stage x rows + z for this wave's 32-row tile
    if (lane < 32) {
        int r = R + lane;
        x_lds[wave][lane][0] = x[r * 3 + 0];
        x_lds[wave][lane][1] = x[r * 3 + 1];
        x_lds[wave][lane][2] = x[r * 3 + 2];
        z_lds[wave][lane]    = z[r];
    }

    // ---- init accumulator with the embedding gather (C/D layout): the 128
    // coalesced L2-hit loads fly while the silu chain below executes.
    f32x16 acc[8];
#pragma unroll
    for (int j = 0; j < 16; ++j) {
        const int rl = (j & 3) + ((j >> 2) << 3) + (h << 2);
        const float* er = emb + (size_t)z_lds[wave][rl] * 256 + l31;
#pragma unroll
        for (int nf = 0; nf < 8; ++nf)
            acc[nf][j] = er[nf * 32];
    }

    // hoisted per-lane weights: this lane computes p columns [lane*4, lane*4+3]
    const int  c0  = lane * 4;
    const f32x4 w1a = *(const f32x4*)(w1 + c0);
    const f32x4 w1b = *(const f32x4*)(w1 + 256 + c0);
    const f32x4 w1c = *(const f32x4*)(w1 + 512 + c0);
    const f32x4 b1v = *(const f32x4*)(b1 + c0);
    float b2v[8], gv[8], bv[8];
#pragma unroll
    for (int nf = 0; nf < 8; ++nf) {
        int c = nf * 32 + l31;
        b2v[nf] = b2[c]; gv[nf] = gamma[c]; bv[nf] = beta[c];
    }

    // p = silu(x @ w1 + b1) -> bf16 LDS tile, XOR-swizzled rows
#pragma unroll
    for (int r = 0; r < 32; ++r) {
        float x0 = x_lds[wave][r][0];
        float x1 = x_lds[wave][r][1];
        float x2 = x_lds[wave][r][2];
        short4_t pv;
#pragma unroll
        for (int j = 0; j < 4; ++j) {
            float tv = x0 * w1a[j] + x1 * w1b[j] + x2 * w1c[j] + b1v[j];
            float s  = tv * __builtin_amdgcn_rcpf(1.f + __expf(-tv));
            pv[j] = (short)f2bf(s);
        }
        int off = (r * 512 + lane * 8) ^ ((r & 7) << 4);
        *(short4_t*)(pbuf + off) = pv;
    }

    // GEMM: [32,256] @ [256,256] via mfma_f32_32x32x16_bf16 (acc pre-loaded with emb)
#pragma unroll
    for (int ks = 0; ks < 16; ++ks) {
        int aoff = (l31 * 512 + ks * 32 + h * 16) ^ ((l31 & 7) << 4);
        short8 a = *(const short8*)(pbuf + aoff);
        const unsigned short* bp = w2f + ks * 512 + lane * 8;
#pragma unroll
        for (int nf = 0; nf < 8; ++nf) {
            short8 b = *(const short8*)(bp + nf * 8192);
            acc[nf] = __builtin_amdgcn_mfma_f32_32x32x16_bf16(a, b, acc[nf], 0, 0, 0);
        }
    }

    // epilogue: h = acc + b2 ; LayerNorm ; NON-TEMPORAL stores (bypass L2
    // write-allocate -> kills the RFO fetch that doubled HBM traffic).
#pragma unroll
    for (int j = 0; j < 16; ++j) {
        const int rl = (j & 3) + ((j >> 2) << 3) + (h << 2);
        float hv[8];
        float hsum = 0.f, hsq = 0.f;
#pragma unroll
        for (int nf = 0; nf < 8; ++nf) {
            float v = acc[nf][j] + b2v[nf];
            hv[nf] = v; hsum += v; hsq += v * v;
        }
#pragma unroll
        for (int d = 1; d < 32; d <<= 1) {    // reduce within lane-half (row-local)
            hsum += __shfl_xor(hsum, d, 64);
            hsq  += __shfl_xor(hsq,  d, 64);
        }
        float mu  = hsum * (1.f / 256.f);
        float var = hsq * (1.f / 256.f) - mu * mu;
        float rs  = rsqrtf(var + EPS);
        float* orow = out + (size_t)(R + rl) * 256 + l31;
#pragma unroll
        for (int nf = 0; nf < 8; ++nf)
            __builtin_nontemporal_store((hv[nf] - mu) * rs * gv[nf] + bv[nf],
                                        orow + nf * 32);
    }
}

extern "C" void kernel_launch(void* const* d_in, const int* in_sizes, int n_in,
                              void* d_out, int out_size, void* d_ws, size_t ws_size,
                              hipStream_t stream) {
    const int*   z     = (const int*)d_in[0];
    const float* x     = (const float*)d_in[1];
    const float* emb   = (const float*)d_in[2];
    const float* w1    = (const float*)d_in[3];
    const float* b1    = (const float*)d_in[4];
    const float* w2    = (const float*)d_in[5];
    const float* b2    = (const float*)d_in[6];
    const float* gamma = (const float*)d_in[7];
    const float* beta  = (const float*)d_in[8];
    float* out = (float*)d_out;
    const int N = in_sizes[0];

    unsigned short* w2f = (unsigned short*)d_ws;   // 128 KB fragment-ordered bf16 w2

    prep_w2<<<256, 256, 0, stream>>>(w2, w2f);

    int tiles  = N >> 5;
    int blocks = (tiles + WAVES - 1) / WAVES;      // one tile per wave
    fused_kernel<<<blocks, 256, 0, stream>>>(z, x, emb, w1, b1, w2f, b2, gamma, beta, out, N);
}